// Round 8
// baseline (79.227 us; speedup 1.0000x reference)
//
#include <hip/hip_runtime.h>
#include <hip/hip_bf16.h>
#include <math.h>

#define N_ 4096
#define L_ 32
#define K_ 8
#define Dc_ 64
#define Db_ 64
#define Dd_ 16
#define C_ 8
#define B_ 32
#define M_ 1000
#define LOG2PI_ 1.8378770664093453f

// output layout (floats): [0]=-elbo [1]=LL [2]=KL_z [3]=KL_s
// [4 .. 4+N*K) = rik ; then term_1 (M), term_2 (M), term_3 (M)
#define OUT_RIK 4
#define OUT_T1 (4 + N_ * K_)

// ws float-offsets
#define WS_PART 0                 // 32*64*48 = 98304 floats: per (b, rt) 3x16 (k-summed)
#define WS_LLP  98304             // 1024 floats: per-block LL partials
#define WS_CNT  99328             // 33 unsigned counters (zeroed by memset node each call)

typedef __attribute__((ext_vector_type(8))) short short8v;
typedef __attribute__((ext_vector_type(4))) float f32x4;

__device__ inline unsigned short f2bf(float f) {
    unsigned u = __builtin_bit_cast(unsigned, f);
    unsigned r = u + 0x7FFFu + ((u >> 16) & 1u);   // round-to-nearest-even
    return (unsigned short)(r >> 16);
}

__device__ inline unsigned short bf16u(float x) {
    __hip_bfloat16 h = __float2bfloat16(x);        // RNE, lowers to v_cvt_pk when paired
    return __builtin_bit_cast(unsigned short, h);
}

__device__ inline short8v cvt8(float4 a, float4 b) {
    short8v r;
    r[0] = (short)bf16u(a.x); r[1] = (short)bf16u(a.y);
    r[2] = (short)bf16u(a.z); r[3] = (short)bf16u(a.w);
    r[4] = (short)bf16u(b.x); r[5] = (short)bf16u(b.y);
    r[6] = (short)bf16u(b.z); r[7] = (short)bf16u(b.w);
    return r;
}

// ---------------- fused kernel: grid (32 mt, 32 b); 512 thr = 8 waves ----------------
__global__ __launch_bounds__(512) void mm_fused(
    const int* __restrict__ pidx,
    const float* __restrict__ Xc, const float* __restrict__ Xb, const int* __restrict__ Xd,
    const float* __restrict__ qm_all, const float* __restrict__ qlv_all,
    const float* __restrict__ qs_all,
    const float* __restrict__ pm_all, const float* __restrict__ pv_all,
    const float* __restrict__ pmu_all,
    const float* __restrict__ Wg, const float* __restrict__ bg, const float* __restrict__ lvg,
    const float* __restrict__ Wb, const float* __restrict__ bb,
    const float* __restrict__ Wd, const float* __restrict__ bd,
    const float* __restrict__ eps,
    float* __restrict__ out, float* __restrict__ ws)
{
    const int tid = threadIdx.x, w = tid >> 6, lane = tid & 63;
    const int mt = blockIdx.x, b = blockIdx.y;
    const int l15 = lane & 15, lg = lane >> 4;
    const int fr = 4 * lg;
    const int start = B_ * pidx[0];
    unsigned* cnt = (unsigned*)(ws + WS_CNT);

    __shared__ __align__(16) unsigned int zu[512];     // 2 tiles * 512 bf16
    __shared__ __align__(16) float scin[2048];         // bias (-Xc for f<64) per (k,f)
    __shared__ __align__(16) float siv[512];
    __shared__ float sqk[8];
    __shared__ float sred[8][2][2][16];
    __shared__ float llred[8];
    __shared__ int sflag;
    __shared__ float sfin[8], sll[8], sc1k[8], sllc[4];
    __shared__ float skl2[B_], sks2[B_];

    // ---- stage z frags, cinit (bias, -Xc folded), iv, qs ----
    if (tid < 256) {
        int m_loc = tid >> 3, l0 = (tid & 7) * 4;
        int m_glob = mt * 32 + m_loc;
        float4 e = make_float4(0.f, 0.f, 0.f, 0.f);
        if (m_glob < M_) e = *(const float4*)(eps + ((size_t)b * M_ + m_glob) * L_ + l0);
        float4 qm4 = *(const float4*)(qm_all + (size_t)(start + b) * L_ + l0);
        float4 ql4 = *(const float4*)(qlv_all + (size_t)(start + b) * L_ + l0);
        float z0 = qm4.x + __expf(0.5f * ql4.x) * e.x;
        float z1 = qm4.y + __expf(0.5f * ql4.y) * e.y;
        float z2 = qm4.z + __expf(0.5f * ql4.z) * e.z;
        float z3 = qm4.w + __expf(0.5f * ql4.w) * e.w;
        unsigned u0 = (unsigned)f2bf(z0) | ((unsigned)f2bf(z1) << 16);
        unsigned u1 = (unsigned)f2bf(z2) | ((unsigned)f2bf(z3) << 16);
        int widx = (m_loc >> 4) * 256 + ((l0 >> 3) * 16 + (m_loc & 15)) * 4 + ((l0 & 7) >> 1);
        zu[widx] = u0; zu[widx + 1] = u1;
    }
    {   // cinit: k = tid>>6, f = (tid&63)*4 ; read bias direct from global
        int k = tid >> 6, f = (tid & 63) * 4;
        float4 bv;
        if (f < 64) {
            bv = *(const float4*)(bg + k * 64 + f);
            float4 xc = *(const float4*)(Xc + b * 64 + f);
            bv.x -= xc.x; bv.y -= xc.y; bv.z -= xc.z; bv.w -= xc.w;
        } else if (f < 128) {
            bv = *(const float4*)(bb + k * 64 + (f - 64));
        } else {
            bv = *(const float4*)(bd + k * 128 + (f - 128));
        }
        ((float4*)scin)[tid] = bv;
    }
    if (tid < 128) {
        float4 lv4 = *(const float4*)(lvg + tid * 4);
        float4 r;
        r.x = __expf(-lv4.x); r.y = __expf(-lv4.y);
        r.z = __expf(-lv4.z); r.w = __expf(-lv4.w);
        ((float4*)siv)[tid] = r;
    }
    if (tid < 8) sqk[tid] = qs_all[(size_t)(start + b) * K_ + tid];
    __syncthreads();

    const short8v zb0 = *(const short8v*)((const unsigned short*)zu + lane * 8);
    const short8v zb1 = *(const short8v*)((const unsigned short*)zu + 512 + lane * 8);

    // ---- hoisted constants ----
    const float4 xf = *(const float4*)(Xb + b * 64 + (w & 3) * 16 + fr);  // used when w>=4
    const int d3 = 2 * w + (lg >> 1);
    const int xd = Xd[b * 16 + d3];
    const int cc0 = 4 * (lg & 1);
    float4 is3;
    is3.x = (cc0 + 0 == xd) ? 1.f : 0.f;  is3.y = (cc0 + 1 == xd) ? 1.f : 0.f;
    is3.z = (cc0 + 2 == xd) ? 1.f : 0.f;  is3.w = (cc0 + 3 == xd) ? 1.f : 0.f;

    // weight addressing (direct global, L2-resident)
    const float* baseA = (w < 4) ? Wg : Wb;
    const size_t offA = (size_t)((w & 3) * 16 + l15) * 32 + lg * 8;
    const size_t offB = (size_t)(w * 16 + l15) * 32 + lg * 8;

    float ta0 = 0.f, ta1 = 0.f, tb0 = 0.f, tb1 = 0.f, ll0 = 0.f, ll1 = 0.f;

    #pragma unroll 2
    for (int k = 0; k < K_; ++k) {
        float4 ra0 = *(const float4*)(baseA + k * 2048 + offA);
        float4 ra1 = *(const float4*)(baseA + k * 2048 + offA + 4);
        float4 rb0 = *(const float4*)(Wd + k * 4096 + offB);
        float4 rb1 = *(const float4*)(Wd + k * 4096 + offB + 4);
        const short8v wfA = cvt8(ra0, ra1);
        const short8v wfB = cvt8(rb0, rb1);
        const float4 cA = *(const float4*)(scin + k * 256 + w * 16 + fr);
        const float4 cB = *(const float4*)(scin + k * 256 + (8 + w) * 16 + fr);
        const float qkv = sqk[k];

        const f32x4 ciA = {cA.x, cA.y, cA.z, cA.w};
        const f32x4 ciB = {cB.x, cB.y, cB.z, cB.w};
        f32x4 d00 = __builtin_amdgcn_mfma_f32_16x16x32_bf16(wfA, zb0, ciA, 0, 0, 0);
        f32x4 d01 = __builtin_amdgcn_mfma_f32_16x16x32_bf16(wfA, zb1, ciA, 0, 0, 0);
        f32x4 d10 = __builtin_amdgcn_mfma_f32_16x16x32_bf16(wfB, zb0, ciB, 0, 0, 0);
        f32x4 d11 = __builtin_amdgcn_mfma_f32_16x16x32_bf16(wfB, zb1, ciB, 0, 0, 0);

        if (w < 4) {             // Gaussian: d = (mean+bias-x) already
            const float4 iv4 = *(const float4*)(siv + k * 64 + w * 16 + fr);
            float s0 = 0.f, s1 = 0.f;
            s0 = fmaf(d00[0] * d00[0], iv4.x, s0); s1 = fmaf(d01[0] * d01[0], iv4.x, s1);
            s0 = fmaf(d00[1] * d00[1], iv4.y, s0); s1 = fmaf(d01[1] * d01[1], iv4.y, s1);
            s0 = fmaf(d00[2] * d00[2], iv4.z, s0); s1 = fmaf(d01[2] * d01[2], iv4.z, s1);
            s0 = fmaf(d00[3] * d00[3], iv4.w, s0); s1 = fmaf(d01[3] * d01[3], iv4.w, s1);
            ta0 += s0; ta1 += s1;
            const float qm5 = -0.5f * qkv;
            ll0 = fmaf(qm5, s0, ll0); ll1 = fmaf(qm5, s1, ll1);
        } else {                 // Bernoulli
            float s0 = 0.f, s1 = 0.f, lgt, sp;
            lgt = d00[0]; sp = fmaxf(lgt, 0.f) + __logf(1.f + __expf(-fabsf(lgt))); s0 += xf.x * lgt - sp;
            lgt = d00[1]; sp = fmaxf(lgt, 0.f) + __logf(1.f + __expf(-fabsf(lgt))); s0 += xf.y * lgt - sp;
            lgt = d00[2]; sp = fmaxf(lgt, 0.f) + __logf(1.f + __expf(-fabsf(lgt))); s0 += xf.z * lgt - sp;
            lgt = d00[3]; sp = fmaxf(lgt, 0.f) + __logf(1.f + __expf(-fabsf(lgt))); s0 += xf.w * lgt - sp;
            lgt = d01[0]; sp = fmaxf(lgt, 0.f) + __logf(1.f + __expf(-fabsf(lgt))); s1 += xf.x * lgt - sp;
            lgt = d01[1]; sp = fmaxf(lgt, 0.f) + __logf(1.f + __expf(-fabsf(lgt))); s1 += xf.y * lgt - sp;
            lgt = d01[2]; sp = fmaxf(lgt, 0.f) + __logf(1.f + __expf(-fabsf(lgt))); s1 += xf.z * lgt - sp;
            lgt = d01[3]; sp = fmaxf(lgt, 0.f) + __logf(1.f + __expf(-fabsf(lgt))); s1 += xf.w * lgt - sp;
            ta0 += s0; ta1 += s1;
            ll0 = fmaf(qkv, s0, ll0); ll1 = fmaf(qkv, s1, ll1);
        }

        // categorical tile (all waves)
        {
            float e4 = __expf(d10[0]) + __expf(d10[1]) + __expf(d10[2]) + __expf(d10[3]);
            float se = e4 + __shfl_xor(e4, 16, 64);
            float u  = is3.x * d10[0] + is3.y * d10[1] + is3.z * d10[2] + is3.w * d10[3];
            float tm = u - 0.5f * __logf(se);
            tb0 += tm; ll0 = fmaf(qkv, tm, ll0);
        }
        {
            float e4 = __expf(d11[0]) + __expf(d11[1]) + __expf(d11[2]) + __expf(d11[3]);
            float se = e4 + __shfl_xor(e4, 16, 64);
            float u  = is3.x * d11[0] + is3.y * d11[1] + is3.z * d11[2] + is3.w * d11[3];
            float tm = u - 0.5f * __logf(se);
            tb1 += tm; ll1 = fmaf(qkv, tm, ll1);
        }
    }

    // ---- deferred masking + reductions ----
    const bool ok0 = (mt * 32 + l15)      < M_;
    const bool ok1 = (mt * 32 + 16 + l15) < M_;
    if (!ok0) { ta0 = 0.f; tb0 = 0.f; ll0 = 0.f; }
    if (!ok1) { ta1 = 0.f; tb1 = 0.f; ll1 = 0.f; }

    float tar0 = ta0 + __shfl_xor(ta0, 16, 64); tar0 += __shfl_xor(tar0, 32, 64);
    float tar1 = ta1 + __shfl_xor(ta1, 16, 64); tar1 += __shfl_xor(tar1, 32, 64);
    float tbr0 = tb0 + __shfl_xor(tb0, 16, 64); tbr0 += __shfl_xor(tbr0, 32, 64);
    float tbr1 = tb1 + __shfl_xor(tb1, 16, 64); tbr1 += __shfl_xor(tbr1, 32, 64);
    float llv = ll0 + ll1;
    #pragma unroll
    for (int ofs = 1; ofs < 64; ofs <<= 1) llv += __shfl_xor(llv, ofs, 64);

    if (lane < 16) {
        sred[w][0][0][l15] = tar0; sred[w][1][0][l15] = tar1;
        sred[w][0][1][l15] = tbr0; sred[w][1][1][l15] = tbr1;
    }
    if (lane == 0) llred[w] = llv;
    __syncthreads();

    if (tid < 96) {
        int i = tid >> 5, tile = (tid >> 4) & 1, cx = tid & 15;
        int rt = mt * 2 + tile;
        float vout;
        if (i == 0) {
            vout = sred[0][tile][0][cx] + sred[1][tile][0][cx]
                 + sred[2][tile][0][cx] + sred[3][tile][0][cx];   // raw Gaussian quad sum
        } else if (i == 1) {
            vout = sred[4][tile][0][cx] + sred[5][tile][0][cx]
                 + sred[6][tile][0][cx] + sred[7][tile][0][cx];
        } else {
            vout = 0.f;
            #pragma unroll
            for (int ww = 0; ww < 8; ++ww) vout += sred[ww][tile][1][cx];
        }
        ws[WS_PART + ((size_t)b * 64 + rt) * 48 + i * 16 + cx] = vout;
    }
    if (tid == 96) {
        float s = 0.f;
        #pragma unroll
        for (int ww = 0; ww < 8; ++ww) s += llred[ww];
        ws[WS_LLP + b * 32 + mt] = s;           // const term added in global finalize
    }

    // ---- rik (32 entries per block) ----
    if (tid < 32) {
        int i = (b * 32 + mt) * 32 + tid;       // [0, N*K)
        int r = i >> 3, c = i & 7;
        float v = 0.f;
        if (r >= start && r < start + B_) {
            const float* row = qs_all + (size_t)r * K_;
            float mx = row[0];
            #pragma unroll
            for (int jj = 1; jj < K_; ++jj) mx = fmaxf(mx, row[jj]);
            float se = 0.f;
            #pragma unroll
            for (int jj = 0; jj < K_; ++jj) se += __expf(row[jj] - mx);
            v = __expf(row[c] - mx) / se;
        }
        out[OUT_RIK + i] = v;
    }

    // ---- semaphores ----
    __syncthreads();
    if (tid == 0) {
        __threadfence();
        unsigned o1 = atomicAdd(cnt + mt, 1u);
        unsigned o2 = atomicAdd(cnt + 32, 1u);
        sflag = ((o1 == 31u) ? 1 : 0) | ((o2 == 1023u) ? 2 : 0);
    }
    __syncthreads();
    const int flg = sflag;

    // ---- per-mt finalize: term_i for this block's 32 rows ----
    if (flg & 1) {
        __threadfence();
        float c1v = LOG2PI_ + lvg[tid];
        #pragma unroll
        for (int ofs = 1; ofs < 64; ofs <<= 1) c1v += __shfl_xor(c1v, ofs, 64);
        if (lane == 0) sfin[w] = c1v;
        __syncthreads();
        float C1sum = 0.f;
        #pragma unroll
        for (int ww = 0; ww < 8; ++ww) C1sum += sfin[ww];
        if (tid < 96) {
            int i = tid >> 5, cx = tid & 31;
            int m = mt * 32 + cx;
            if (m < M_) {
                int rt = mt * 2 + (cx >> 4), cxx = cx & 15;
                float s = 0.f;
                #pragma unroll 8
                for (int b2 = 0; b2 < 32; ++b2)
                    s += ws[WS_PART + ((size_t)b2 * 64 + rt) * 48 + i * 16 + cxx];
                float vout = (i == 0) ? (-0.5f * (32.f * C1sum + s)) : s;
                out[OUT_T1 + i * M_ + m] = vout;
            }
        }
    }

    // ---- global finalize: LL / KL / elbo ----
    if (flg & 2) {
        __threadfence();
        float v = ws[WS_LLP + tid] + ws[WS_LLP + 512 + tid];
        #pragma unroll
        for (int ofs = 1; ofs < 64; ofs <<= 1) v += __shfl_xor(v, ofs, 64);
        if (lane == 0) sll[w] = v;
        float c1v = LOG2PI_ + lvg[tid];        // wave w covers k=w (64 entries)
        #pragma unroll
        for (int ofs = 1; ofs < 64; ofs <<= 1) c1v += __shfl_xor(c1v, ofs, 64);
        if (lane == 0) sc1k[w] = c1v;
        __syncthreads();
        if (tid < 256) {
            float lc = qs_all[(size_t)(start + (tid >> 3)) * K_ + (tid & 7)] * sc1k[tid & 7];
            #pragma unroll
            for (int ofs = 1; ofs < 64; ofs <<= 1) lc += __shfl_xor(lc, ofs, 64);
            if (lane == 0) sllc[w] = lc;
        }
        if (tid < B_) {
            int r = start + tid;
            float kl = 0.f;
            for (int l = 0; l < L_; ++l) {
                float qmv = qm_all[(size_t)r * L_ + l];
                float qlv = qlv_all[(size_t)r * L_ + l];
                float mp  = pm_all[(size_t)r * L_ + l];
                float vp  = pv_all[(size_t)r * L_ + l];
                float d   = qmv - mp;
                kl += __logf(vp) - qlv + (__expf(qlv) + d * d) / vp - 1.f;
            }
            skl2[tid] = 0.5f * kl;
            float qsum = 0.f, psum = 0.f;
            #pragma unroll
            for (int j = 0; j < K_; ++j) {
                qsum += qs_all[(size_t)r * K_ + j];
                psum += pmu_all[(size_t)r * K_ + j];
            }
            float ks = 0.f;
            #pragma unroll
            for (int j = 0; j < K_; ++j) {
                float qn = qs_all[(size_t)r * K_ + j] / qsum;
                float pn = pmu_all[(size_t)r * K_ + j] / psum;
                ks += qn * (__logf(qn) - __logf(pn));
            }
            sks2[tid] = ks;
        }
        __syncthreads();
        if (tid == 0) {
            float LL = 0.f;
            #pragma unroll
            for (int ww = 0; ww < 8; ++ww) LL += sll[ww];
            float lcs = 0.f;
            #pragma unroll
            for (int ww = 0; ww < 4; ++ww) lcs += sllc[ww];
            LL -= 0.5f * (float)M_ * lcs;
            float sklz = 0.f, skls = 0.f;
            for (int i = 0; i < B_; ++i) { sklz += skl2[i]; skls += sks2[i]; }
            float elbo = LL - sklz - skls;
            out[0] = -elbo;
            out[1] = LL;
            out[2] = skl2[B_ - 1];
            out[3] = sks2[B_ - 1];
        }
    }
}

extern "C" void kernel_launch(void* const* d_in, const int* in_sizes, int n_in,
                              void* d_out, int out_size, void* d_ws, size_t ws_size,
                              hipStream_t stream)
{
    (void)in_sizes; (void)n_in; (void)out_size; (void)ws_size;
    const int*   pidx = (const int*)d_in[0];
    const float* Xc   = (const float*)d_in[1];
    const float* Xb   = (const float*)d_in[2];
    const int*   Xd   = (const int*)d_in[3];
    const float* qm   = (const float*)d_in[4];
    const float* qlv  = (const float*)d_in[5];
    const float* qs   = (const float*)d_in[6];
    const float* pm   = (const float*)d_in[7];
    const float* pv   = (const float*)d_in[8];
    const float* pmu  = (const float*)d_in[9];
    const float* Wg   = (const float*)d_in[10];
    const float* bg   = (const float*)d_in[11];
    const float* lvg  = (const float*)d_in[12];
    const float* Wb   = (const float*)d_in[13];
    const float* bb   = (const float*)d_in[14];
    const float* Wd   = (const float*)d_in[15];
    const float* bd   = (const float*)d_in[16];
    const float* eps  = (const float*)d_in[17];
    float* out = (float*)d_out;
    float* ws  = (float*)d_ws;

    // zero the 33 semaphore counters (graph-capturable memset node)
    hipMemsetAsync((char*)d_ws + (size_t)WS_CNT * 4, 0, 33 * 4, stream);

    dim3 grid(32, 32);   // (m-tile-pair of 32 rows, b)
    mm_fused<<<grid, 512, 0, stream>>>(pidx, Xc, Xb, Xd, qm, qlv, qs,
                                       pm, pv, pmu, Wg, bg, lvg, Wb, bb, Wd, bd,
                                       eps, out, ws);
}

// Round 9
// 41.566 us; speedup vs baseline: 1.9061x; 1.9061x over previous
//
#include <hip/hip_runtime.h>
#include <math.h>

#define N_ 4096
#define L_ 32
#define K_ 8
#define Dc_ 64
#define Db_ 64
#define Dd_ 16
#define C_ 8
#define B_ 32
#define M_ 1000
#define LOG2PI_ 1.8378770664093453f

// output layout (floats): [0]=-elbo [1]=LL [2]=KL_z [3]=KL_s
// [4 .. 4+N*K) = rik ; then term_1 (M), term_2 (M), term_3 (M)
#define OUT_RIK 4
#define OUT_T1 (4 + N_ * K_)

// ws float-offsets
#define WS_PART 0                 // 32*64*48 = 98304 floats: per (b, rt) 3x16 (k-summed)
#define WS_LLP  98304             // 512 floats: per-block LL partials (32 b * 16 mt)
#define WS_WP   99328             // 65536 ushorts (32768 floats): bf16 weight frags
#define WS_BIAS (WS_WP + 32768)   // 2048 floats (raw bias per (k,f))
#define WS_IV   (WS_BIAS + 2048)  // 512 floats
#define WS_C1   (WS_IV + 512)     // 9 floats: per-k const1 + [8]=total

typedef __attribute__((ext_vector_type(8))) short short8v;
typedef __attribute__((ext_vector_type(4))) float f32x4;

__device__ inline unsigned short f2bf(float f) {
    unsigned u = __builtin_bit_cast(unsigned, f);
    unsigned r = u + 0x7FFFu + ((u >> 16) & 1u);   // round-to-nearest-even
    return (unsigned short)(r >> 16);
}

// ---------------- prep: W-frags, bias/iv/c1 ----------------
#define PW  65536
#define PB  (PW + 2048)
#define PIV (PB + 512)
#define PC1 (PIV + 9)

__global__ __launch_bounds__(256) void mm_prep(
    const float* __restrict__ Wg, const float* __restrict__ bg, const float* __restrict__ lvg,
    const float* __restrict__ Wb, const float* __restrict__ bb,
    const float* __restrict__ Wd, const float* __restrict__ bd,
    float* __restrict__ ws)
{
    const int t = blockIdx.x * 256 + threadIdx.x;
    unsigned short* wpw = (unsigned short*)(ws + WS_WP);

    if (t < PW) {
        // weight fragment elem: [k][ft][lane][j] ; feature = ft*16+(lane&15); l = (lane>>4)*8+j
        int j = t & 7, lane = (t >> 3) & 63, ft = (t >> 9) & 15, k = t >> 13;
        int f = ft * 16 + (lane & 15);
        int l = (lane >> 4) * 8 + j;
        float w;
        if (f < 64)       w = Wg[((size_t)k * 64 + f) * L_ + l];
        else if (f < 128) w = Wb[((size_t)k * 64 + (f - 64)) * L_ + l];
        else { int d = (f - 128) >> 3, c = f & 7; w = Wd[(((size_t)k * 16 + d) * 8 + c) * L_ + l]; }
        wpw[t] = f2bf(w);
    } else if (t < PB) {
        int i = t - PW; int k = i >> 8, f = i & 255;
        float v;
        if (f < 64)       v = bg[k * 64 + f];
        else if (f < 128) v = bb[k * 64 + f - 64];
        else { int d = (f - 128) >> 3, c = f & 7; v = bd[(k * 16 + d) * 8 + c]; }
        ws[WS_BIAS + i] = v;
    } else if (t < PIV) {
        int i = t - PB;
        ws[WS_IV + i] = __expf(-lvg[i]);
    } else if (t < PC1) {
        int k = t - PIV;
        if (k < 8) {
            float s = 0.f;
            for (int d = 0; d < 64; ++d) s += LOG2PI_ + lvg[k * 64 + d];
            ws[WS_C1 + k] = s;
        } else {
            float s = 0.f;
            for (int i = 0; i < 512; ++i) s += LOG2PI_ + lvg[i];
            ws[WS_C1 + 8] = s;
        }
    }
}

// ---------------- main: grid (16 mt, 32 b); 512 thr = 8 waves ----------------
// Four 16-row m-tiles per block (64 rows). Wave w owns feature-tiles {w, 8+w}.
// Bias (-Xc for Gaussian) folded into the MFMA C operand; per-k loads amortized
// over 8 MFMAs; reductions and masking deferred out of the k-loop.
__global__ __launch_bounds__(512, 2) void mm_main(
    const int* __restrict__ pidx,
    const float* __restrict__ Xc, const float* __restrict__ Xb, const int* __restrict__ Xd,
    const float* __restrict__ qm_all, const float* __restrict__ qlv_all,
    const float* __restrict__ qs_all, const float* __restrict__ eps,
    float* __restrict__ ws)
{
    const int tid = threadIdx.x, w = tid >> 6, lane = tid & 63;
    const int mt = blockIdx.x, b = blockIdx.y;
    const int l15 = lane & 15, lg = lane >> 4;
    const int fr = 4 * lg;
    const int start = B_ * pidx[0];
    const unsigned short* wp = (const unsigned short*)(ws + WS_WP);

    __shared__ __align__(16) unsigned int zu[1024];    // 4 tiles * 512 bf16
    __shared__ __align__(16) float scin[2048];         // bias (-Xc for f<64) per (k,f)
    __shared__ __align__(16) float siv[512];
    __shared__ float sqk[8];
    __shared__ float sred[8][4][2][16];
    __shared__ float llred[8];

    // ---- stage z fragments (512 thr: 64 rows x 8 l-quads) ----
    {
        int m_loc = tid >> 3, l0 = (tid & 7) * 4;
        int m_glob = mt * 64 + m_loc;
        float4 e = make_float4(0.f, 0.f, 0.f, 0.f);
        if (m_glob < M_) e = *(const float4*)(eps + ((size_t)b * M_ + m_glob) * L_ + l0);
        float4 qm4 = *(const float4*)(qm_all + (size_t)(start + b) * L_ + l0);
        float4 ql4 = *(const float4*)(qlv_all + (size_t)(start + b) * L_ + l0);
        float z0 = qm4.x + __expf(0.5f * ql4.x) * e.x;
        float z1 = qm4.y + __expf(0.5f * ql4.y) * e.y;
        float z2 = qm4.z + __expf(0.5f * ql4.z) * e.z;
        float z3 = qm4.w + __expf(0.5f * ql4.w) * e.w;
        unsigned u0 = (unsigned)f2bf(z0) | ((unsigned)f2bf(z1) << 16);
        unsigned u1 = (unsigned)f2bf(z2) | ((unsigned)f2bf(z3) << 16);
        int widx = (m_loc >> 4) * 256 + ((l0 >> 3) * 16 + (m_loc & 15)) * 4 + ((l0 & 7) >> 1);
        zu[widx] = u0; zu[widx + 1] = u1;
    }
    {   // cinit: k = tid>>6, f = (tid&63)*4
        int f = (tid & 63) * 4;
        float4 bv = *(const float4*)(ws + WS_BIAS + tid * 4);
        if (f < 64) {
            float4 xc = *(const float4*)(Xc + b * 64 + f);
            bv.x -= xc.x; bv.y -= xc.y; bv.z -= xc.z; bv.w -= xc.w;
        }
        ((float4*)scin)[tid] = bv;
    }
    if (tid < 128) ((float4*)siv)[tid] = *(const float4*)(ws + WS_IV + tid * 4);
    if (tid < 8)   sqk[tid] = qs_all[(size_t)(start + b) * K_ + tid];
    __syncthreads();

    const unsigned short* zp = (const unsigned short*)zu;
    const short8v zbA = *(const short8v*)(zp + lane * 8);
    const short8v zbB = *(const short8v*)(zp + 512 + lane * 8);
    const short8v zbC = *(const short8v*)(zp + 1024 + lane * 8);
    const short8v zbD = *(const short8v*)(zp + 1536 + lane * 8);

    // ---- hoisted constants ----
    const float4 xf = *(const float4*)(Xb + b * 64 + (w & 3) * 16 + fr);  // used when w>=4
    const int d3 = 2 * w + (lg >> 1);
    const int xd = Xd[b * 16 + d3];
    const int cc0 = 4 * (lg & 1);
    float4 is3;
    is3.x = (cc0 + 0 == xd) ? 1.f : 0.f;  is3.y = (cc0 + 1 == xd) ? 1.f : 0.f;
    is3.z = (cc0 + 2 == xd) ? 1.f : 0.f;  is3.w = (cc0 + 3 == xd) ? 1.f : 0.f;

    float taA = 0.f, taB = 0.f, taC = 0.f, taD = 0.f;
    float tbA = 0.f, tbB = 0.f, tbC = 0.f, tbD = 0.f;
    float llA = 0.f, llB = 0.f, llC = 0.f, llD = 0.f;

#define GAUSS_EPI(dd, ta_, ll_) { \
    float s_ = 0.f; \
    s_ = fmaf(dd[0] * dd[0], iv4.x, s_); \
    s_ = fmaf(dd[1] * dd[1], iv4.y, s_); \
    s_ = fmaf(dd[2] * dd[2], iv4.z, s_); \
    s_ = fmaf(dd[3] * dd[3], iv4.w, s_); \
    ta_ += s_; ll_ = fmaf(qm5, s_, ll_); }

#define BERN_EPI(dd, ta_, ll_) { \
    float s_ = 0.f, lgt_, sp_; \
    lgt_ = dd[0]; sp_ = fmaxf(lgt_, 0.f) + __logf(1.f + __expf(-fabsf(lgt_))); s_ += xf.x * lgt_ - sp_; \
    lgt_ = dd[1]; sp_ = fmaxf(lgt_, 0.f) + __logf(1.f + __expf(-fabsf(lgt_))); s_ += xf.y * lgt_ - sp_; \
    lgt_ = dd[2]; sp_ = fmaxf(lgt_, 0.f) + __logf(1.f + __expf(-fabsf(lgt_))); s_ += xf.z * lgt_ - sp_; \
    lgt_ = dd[3]; sp_ = fmaxf(lgt_, 0.f) + __logf(1.f + __expf(-fabsf(lgt_))); s_ += xf.w * lgt_ - sp_; \
    ta_ += s_; ll_ = fmaf(qkv, s_, ll_); }

#define CAT_EPI(dd, tb_, ll_) { \
    float e4_ = __expf(dd[0]) + __expf(dd[1]) + __expf(dd[2]) + __expf(dd[3]); \
    float se_ = e4_ + __shfl_xor(e4_, 16, 64); \
    float u_  = is3.x * dd[0] + is3.y * dd[1] + is3.z * dd[2] + is3.w * dd[3]; \
    float tm_ = u_ - 0.5f * __logf(se_); \
    tb_ += tm_; ll_ = fmaf(qkv, tm_, ll_); }

    #pragma unroll 2
    for (int k = 0; k < K_; ++k) {
        const short8v wfA = *(const short8v*)(wp + ((size_t)(k * 16 + w))     * 512 + lane * 8);
        const short8v wfB = *(const short8v*)(wp + ((size_t)(k * 16 + 8 + w)) * 512 + lane * 8);
        const float4 cA = *(const float4*)(scin + k * 256 + w * 16 + fr);
        const float4 cB = *(const float4*)(scin + k * 256 + (8 + w) * 16 + fr);
        const float qkv = sqk[k];

        const f32x4 ciA = {cA.x, cA.y, cA.z, cA.w};
        const f32x4 ciB = {cB.x, cB.y, cB.z, cB.w};
        f32x4 dA0 = __builtin_amdgcn_mfma_f32_16x16x32_bf16(wfA, zbA, ciA, 0, 0, 0);
        f32x4 dA1 = __builtin_amdgcn_mfma_f32_16x16x32_bf16(wfA, zbB, ciA, 0, 0, 0);
        f32x4 dA2 = __builtin_amdgcn_mfma_f32_16x16x32_bf16(wfA, zbC, ciA, 0, 0, 0);
        f32x4 dA3 = __builtin_amdgcn_mfma_f32_16x16x32_bf16(wfA, zbD, ciA, 0, 0, 0);
        f32x4 dB0 = __builtin_amdgcn_mfma_f32_16x16x32_bf16(wfB, zbA, ciB, 0, 0, 0);
        f32x4 dB1 = __builtin_amdgcn_mfma_f32_16x16x32_bf16(wfB, zbB, ciB, 0, 0, 0);
        f32x4 dB2 = __builtin_amdgcn_mfma_f32_16x16x32_bf16(wfB, zbC, ciB, 0, 0, 0);
        f32x4 dB3 = __builtin_amdgcn_mfma_f32_16x16x32_bf16(wfB, zbD, ciB, 0, 0, 0);

        if (w < 4) {             // Gaussian: d = (mean+bias-x) already
            const float4 iv4 = *(const float4*)(siv + k * 64 + w * 16 + fr);
            const float qm5 = -0.5f * qkv;
            GAUSS_EPI(dA0, taA, llA)
            GAUSS_EPI(dA1, taB, llB)
            GAUSS_EPI(dA2, taC, llC)
            GAUSS_EPI(dA3, taD, llD)
        } else {                 // Bernoulli
            BERN_EPI(dA0, taA, llA)
            BERN_EPI(dA1, taB, llB)
            BERN_EPI(dA2, taC, llC)
            BERN_EPI(dA3, taD, llD)
        }
        CAT_EPI(dB0, tbA, llA)
        CAT_EPI(dB1, tbB, llB)
        CAT_EPI(dB2, tbC, llC)
        CAT_EPI(dB3, tbD, llD)
    }

    // ---- deferred masking + reductions ----
    const int mrow = mt * 64 + l15;
    if (mrow      >= M_) { taA = 0.f; tbA = 0.f; llA = 0.f; }
    if (mrow + 16 >= M_) { taB = 0.f; tbB = 0.f; llB = 0.f; }
    if (mrow + 32 >= M_) { taC = 0.f; tbC = 0.f; llC = 0.f; }
    if (mrow + 48 >= M_) { taD = 0.f; tbD = 0.f; llD = 0.f; }

    float tarA = taA + __shfl_xor(taA, 16, 64); tarA += __shfl_xor(tarA, 32, 64);
    float tarB = taB + __shfl_xor(taB, 16, 64); tarB += __shfl_xor(tarB, 32, 64);
    float tarC = taC + __shfl_xor(taC, 16, 64); tarC += __shfl_xor(tarC, 32, 64);
    float tarD = taD + __shfl_xor(taD, 16, 64); tarD += __shfl_xor(tarD, 32, 64);
    float tbrA = tbA + __shfl_xor(tbA, 16, 64); tbrA += __shfl_xor(tbrA, 32, 64);
    float tbrB = tbB + __shfl_xor(tbB, 16, 64); tbrB += __shfl_xor(tbrB, 32, 64);
    float tbrC = tbC + __shfl_xor(tbC, 16, 64); tbrC += __shfl_xor(tbrC, 32, 64);
    float tbrD = tbD + __shfl_xor(tbD, 16, 64); tbrD += __shfl_xor(tbrD, 32, 64);
    float llv = llA + llB + llC + llD;
    #pragma unroll
    for (int ofs = 1; ofs < 64; ofs <<= 1) llv += __shfl_xor(llv, ofs, 64);

    if (lane < 16) {
        sred[w][0][0][l15] = tarA; sred[w][1][0][l15] = tarB;
        sred[w][2][0][l15] = tarC; sred[w][3][0][l15] = tarD;
        sred[w][0][1][l15] = tbrA; sred[w][1][1][l15] = tbrB;
        sred[w][2][1][l15] = tbrC; sred[w][3][1][l15] = tbrD;
    }
    if (lane == 0) llred[w] = llv;
    __syncthreads();

    if (tid < 192) {
        int i = tid >> 6, tile = (tid >> 4) & 3, cx = tid & 15;
        int rt = mt * 4 + tile;
        float s;
        if (i == 0) {
            s = sred[0][tile][0][cx] + sred[1][tile][0][cx]
              + sred[2][tile][0][cx] + sred[3][tile][0][cx];   // raw Gaussian quad sum
        } else if (i == 1) {
            s = sred[4][tile][0][cx] + sred[5][tile][0][cx]
              + sred[6][tile][0][cx] + sred[7][tile][0][cx];
        } else {
            s = 0.f;
            #pragma unroll
            for (int ww = 0; ww < 8; ++ww) s += sred[ww][tile][1][cx];
        }
        ws[WS_PART + ((size_t)b * 64 + rt) * 48 + i * 16 + cx] = s;
    }
    if (tid == 192) {
        float s = 0.f;
        #pragma unroll
        for (int ww = 0; ww < 8; ++ww) s += llred[ww];
        float cterm = 0.f;
        #pragma unroll
        for (int k = 0; k < 8; ++k) cterm = fmaf(sqk[k], ws[WS_C1 + k], cterm);
        int nv = M_ - mt * 64; nv = (nv > 64) ? 64 : (nv < 0 ? 0 : nv);
        ws[WS_LLP + b * 16 + mt] = s - 0.5f * cterm * (float)nv;
    }
}

// ---------------- final: block 0 = LL/KL/elbo ; 1..12 = terms ; 13..140 = rik ----------------
__global__ __launch_bounds__(256) void mm_final(
    const int* __restrict__ pidx,
    const float* __restrict__ qm_all, const float* __restrict__ qlv_all,
    const float* __restrict__ qs_all,
    const float* __restrict__ pm_all, const float* __restrict__ pv_all,
    const float* __restrict__ pmu_all,
    const float* __restrict__ ws, float* __restrict__ out)
{
    const int tid = threadIdx.x;
    if (blockIdx.x == 0) {
        __shared__ float wred[4];
        __shared__ float skl[B_], sks[B_];
        const int start = B_ * pidx[0];
        float v = ws[WS_LLP + tid] + ws[WS_LLP + 256 + tid];
        #pragma unroll
        for (int ofs = 1; ofs < 64; ofs <<= 1) v += __shfl_xor(v, ofs, 64);
        if ((tid & 63) == 0) wred[tid >> 6] = v;

        if (tid < B_) {
            int r = start + tid;
            float kl = 0.f;
            for (int l = 0; l < L_; ++l) {
                float qmv = qm_all[(size_t)r * L_ + l];
                float qlv = qlv_all[(size_t)r * L_ + l];
                float mp  = pm_all[(size_t)r * L_ + l];
                float vp  = pv_all[(size_t)r * L_ + l];
                float d   = qmv - mp;
                kl += __logf(vp) - qlv + (__expf(qlv) + d * d) / vp - 1.f;
            }
            skl[tid] = 0.5f * kl;

            float qsum = 0.f, psum = 0.f;
            #pragma unroll
            for (int j = 0; j < K_; ++j) {
                qsum += qs_all[(size_t)r * K_ + j];
                psum += pmu_all[(size_t)r * K_ + j];
            }
            float ks = 0.f;
            #pragma unroll
            for (int j = 0; j < K_; ++j) {
                float qn = qs_all[(size_t)r * K_ + j] / qsum;
                float pn = pmu_all[(size_t)r * K_ + j] / psum;
                ks += qn * (__logf(qn) - __logf(pn));
            }
            sks[tid] = ks;
        }
        __syncthreads();
        if (tid == 0) {
            float LL = wred[0] + wred[1] + wred[2] + wred[3];
            float sklz = 0.f, skls = 0.f;
            for (int i = 0; i < B_; ++i) { sklz += skl[i]; skls += sks[i]; }
            float elbo = LL - sklz - skls;
            out[0] = -elbo;
            out[1] = LL;
            out[2] = skl[B_ - 1];
            out[3] = sks[B_ - 1];
        }
    } else if (blockIdx.x <= 12) {
        int g = (blockIdx.x - 1) * 256 + tid;
        if (g < 3 * M_) {
            int i = g / M_, m = g % M_;
            int rt = m >> 4, cx = m & 15;
            float s = 0.f;
            #pragma unroll 8
            for (int b2 = 0; b2 < 32; ++b2)
                s += ws[WS_PART + ((size_t)b2 * 64 + rt) * 48 + i * 16 + cx];
            if (i == 0) s = -0.5f * (32.f * ws[WS_C1 + 8] + s);
            out[OUT_T1 + i * M_ + m] = s;
        }
    } else {
        int i = (blockIdx.x - 13) * 256 + tid;   // [0, N*K)
        int r = i >> 3, c = i & 7;
        int start = B_ * pidx[0];
        float v = 0.f;
        if (r >= start && r < start + B_) {
            const float* row = qs_all + (size_t)r * K_;
            float mx = row[0];
            #pragma unroll
            for (int jj = 1; jj < K_; ++jj) mx = fmaxf(mx, row[jj]);
            float se = 0.f;
            #pragma unroll
            for (int jj = 0; jj < K_; ++jj) se += __expf(row[jj] - mx);
            v = __expf(row[c] - mx) / se;
        }
        out[OUT_RIK + i] = v;
    }
}

extern "C" void kernel_launch(void* const* d_in, const int* in_sizes, int n_in,
                              void* d_out, int out_size, void* d_ws, size_t ws_size,
                              hipStream_t stream)
{
    (void)in_sizes; (void)n_in; (void)out_size; (void)ws_size;
    const int*   pidx = (const int*)d_in[0];
    const float* Xc   = (const float*)d_in[1];
    const float* Xb   = (const float*)d_in[2];
    const int*   Xd   = (const int*)d_in[3];
    const float* qm   = (const float*)d_in[4];
    const float* qlv  = (const float*)d_in[5];
    const float* qs   = (const float*)d_in[6];
    const float* pm   = (const float*)d_in[7];
    const float* pv   = (const float*)d_in[8];
    const float* pmu  = (const float*)d_in[9];
    const float* Wg   = (const float*)d_in[10];
    const float* bg   = (const float*)d_in[11];
    const float* lvg  = (const float*)d_in[12];
    const float* Wb   = (const float*)d_in[13];
    const float* bb   = (const float*)d_in[14];
    const float* Wd   = (const float*)d_in[15];
    const float* bd   = (const float*)d_in[16];
    const float* eps  = (const float*)d_in[17];
    float* out = (float*)d_out;
    float* ws  = (float*)d_ws;

    mm_prep<<<(PC1 + 255) / 256, 256, 0, stream>>>(Wg, bg, lvg, Wb, bb, Wd, bd, ws);

    dim3 grid(16, 32);   // (64-row m-group, b)
    mm_main<<<grid, 512, 0, stream>>>(pidx, Xc, Xb, Xd, qm, qlv, qs, eps, ws);

    mm_final<<<141, 256, 0, stream>>>(pidx, qm, qlv, qs, pm, pv, pmu, ws, out);
}